// Round 7
// baseline (367.175 us; speedup 1.0000x reference)
//
#include <hip/hip_runtime.h>
#include <hip/hip_bf16.h>

typedef __attribute__((ext_vector_type(8))) short short8;
typedef __attribute__((ext_vector_type(4))) float float4v;
typedef __attribute__((ext_vector_type(4))) unsigned int uint4v;

#define DDIM 1024

__device__ __forceinline__ unsigned short f2bf(float f) {
  unsigned u = __builtin_bit_cast(unsigned, f);
  unsigned r = (u + 0x7fffu + ((u >> 16) & 1u)) >> 16;   // RNE
  return (unsigned short)r;
}
__device__ __forceinline__ unsigned pk2(float lo, float hi) {
  return (unsigned)f2bf(lo) | ((unsigned)f2bf(hi) << 16);
}
__device__ __forceinline__ void cvt8(const float* src, unsigned short* dst) {
  float4v a = *(const float4v*)(src);
  float4v b = *(const float4v*)(src + 4);
  uint4v pk;
  pk.x = pk2(a.x, a.y); pk.y = pk2(a.z, a.w);
  pk.z = pk2(b.x, b.y); pk.w = pk2(b.z, b.w);
  *(uint4v*)dst = pk;
}

// ---- prepass: W (1M) + eth (32M) fp32 -> bf16 in workspace ----
__global__ __launch_bounds__(256) void convert_all(const float* __restrict__ W,
                                                   const float* __restrict__ eth,
                                                   unsigned short* __restrict__ Wb,
                                                   unsigned short* __restrict__ ethB) {
  int b = blockIdx.x;
  if (b < 512) {
    size_t i = ((size_t)b * 256 + threadIdx.x) * 8;
    cvt8(W + i, Wb + i);
  } else {
    size_t i = ((size_t)(b - 512) * 256 + threadIdx.x) * 8;
    cvt8(eth + i, ethB + i);
  }
}
__global__ __launch_bounds__(256) void convert_w(const float* __restrict__ W,
                                                 unsigned short* __restrict__ Wb) {
  size_t i = ((size_t)blockIdx.x * 256 + threadIdx.x) * 8;
  cvt8(W + i, Wb + i);
}

// ---- main: 128 rows x 128 d-cols per block, K=1024 ----
// XCD remap (verified: FETCH 336->122 MB): mg=(b&7)|((b>>6)<<3), dt=(b>>3)&7.
// Round 7: 3-BUFFER, ONE-BARRIER loop. The 2-phase {vmcnt, bar, reads,
// lgkmcnt(0), bar, stage} structure was the wall (m233-style: stall is
// structural; stagger A/B in round 6 proved it's not inter-block lockstep).
// New iter: vmcnt(4) [my tile-i DMAs done] -> s_barrier [publishes everyone's
// tile-i DMAs AND frees the buffer read last iter] -> stage(i+2) into freed
// buffer -> ds_read buf[i%3] -> MFMA. Reads retire before each wave's MFMAs
// issue, hence before it reaches the next barrier -> no second barrier needed.
// DMAs get ~2 iters of slack. LDS 49 KB -> 3 blocks/CU (= measured occupancy
// of the old version anyway).
__global__ __launch_bounds__(256, 4) void bilinear_bf16(const float* __restrict__ elg,
                                                        const unsigned short* __restrict__ ethB,
                                                        const unsigned short* __restrict__ Wb,
                                                        float* __restrict__ out) {
  __shared__ unsigned short Wbuf[3][128 * 32];  // 24 KB
  __shared__ unsigned short ethL[3][128 * 32];  // 24 KB
  __shared__ float wsum[4][64];                 // 1 KB

  const int tid  = threadIdx.x;
  const int lane = tid & 63;
  const int w    = tid >> 6;
  const int quad = lane >> 4;
  const int l15  = lane & 15;
  const int rowhalf = w >> 1;       // wave's 64-row half
  const int colhalf = w & 1;        // wave's 64-col half
  const int b  = blockIdx.x;
  const int mg = (b & 7) | ((b >> 6) << 3);   // m-group 0..255
  const int dt = (b >> 3) & 7;                // d-tile 0..7
  const int m0 = mg * 128;
  const int d0 = dt * 128;
  const int koff = ((b >> 8) & 3) * 8;        // K-phase stagger (neutral, kept)
  const int wr = lane >> 2, wu = lane & 3;    // DMA row/unit role

  // stage K-chunk ek into buffer buf: 4 DMA instrs/thread, 16 KB total
  auto stage = [&](int ek, int buf) {
    const int e0 = ek * 32;
#pragma unroll
    for (int j = 0; j < 2; ++j) {
      const int R0 = w * 16 + j * 64;        // 16-row slab per wave-instr
      const int r  = R0 + wr;
      const int ug = wu ^ ((r >> 1) & 3);    // swizzle on the GLOBAL side
      const unsigned short* gw = Wb   + (size_t)(d0 + r) * DDIM + e0 + ug * 8;
      const unsigned short* ge = ethB + (size_t)(m0 + r) * DDIM + e0 + ug * 8;
      unsigned short* lw = &Wbuf[buf][R0 * 32 + lane * 8];
      unsigned short* le = &ethL[buf][R0 * 32 + lane * 8];
      __builtin_amdgcn_global_load_lds(
          (const __attribute__((address_space(1))) unsigned int*)gw,
          (__attribute__((address_space(3))) unsigned int*)lw, 16, 0, 0);
      __builtin_amdgcn_global_load_lds(
          (const __attribute__((address_space(1))) unsigned int*)ge,
          (__attribute__((address_space(3))) unsigned int*)le, 16, 0, 0);
    }
  };

  float4v acc[4][4];
#pragma unroll
  for (int ct = 0; ct < 4; ++ct)
#pragma unroll
    for (int rt = 0; rt < 4; ++rt)
      acc[ct][rt] = (float4v){0.f, 0.f, 0.f, 0.f};

  // prologue: tiles 0,1 -> buf0,buf1 (8 DMAs/thread outstanding)
  stage(koff, 0);
  stage((koff + 1) & 31, 1);

  int cur = 0, stg = 2;                      // read buf, stage-target buf
  for (int i = 0; i < 32; ++i) {
    // my tile-i DMAs are the oldest outstanding; tile i+1's stay in flight
    if (i < 31) asm volatile("s_waitcnt vmcnt(4)" ::: "memory");
    else        asm volatile("s_waitcnt vmcnt(0)" ::: "memory");
    __builtin_amdgcn_s_barrier();            // tile i published; buf[stg] free
    if (i < 30) stage((i + 2 + koff) & 31, stg);  // overlaps reads + MFMA

    short8 aF[4], bF[4];
#pragma unroll
    for (int rt = 0; rt < 4; ++rt) {         // A[m=l15][k=quad*8+j]
      int r  = rowhalf * 64 + rt * 16 + l15;
      int pu = quad ^ ((r >> 1) & 3);
      aF[rt] = *(const short8*)&ethL[cur][r * 32 + pu * 8];
    }
#pragma unroll
    for (int ct = 0; ct < 4; ++ct) {         // B[k][n=l15] = W row d
      int r  = colhalf * 64 + ct * 16 + l15;
      int pu = quad ^ ((r >> 1) & 3);
      bF[ct] = *(const short8*)&Wbuf[cur][r * 32 + pu * 8];
    }

    __builtin_amdgcn_s_setprio(1);
#pragma unroll
    for (int ct = 0; ct < 4; ++ct)
#pragma unroll
      for (int rt = 0; rt < 4; ++rt)
        acc[ct][rt] = __builtin_amdgcn_mfma_f32_16x16x32_bf16(aF[rt], bF[ct], acc[ct][rt], 0, 0, 0);
    __builtin_amdgcn_s_setprio(0);
    // reads already drained (MFMA deps); cheap insurance against motion:
    asm volatile("s_waitcnt lgkmcnt(0)" ::: "memory");

    cur = (cur == 2) ? 0 : cur + 1;
    stg = (stg == 2) ? 0 : stg + 1;
  }

  // fused epilogue: p[m] = sum_col elg[m][col] * u[m][col] over this d-tile
  float p[16];
#pragma unroll
  for (int j = 0; j < 16; ++j) p[j] = 0.f;
#pragma unroll
  for (int ct = 0; ct < 4; ++ct) {
    int col = d0 + colhalf * 64 + ct * 16 + l15;
#pragma unroll
    for (int rt = 0; rt < 4; ++rt) {
      const float* ep = elg + (size_t)(m0 + rowhalf * 64 + rt * 16 + quad * 4) * DDIM + col;
#pragma unroll
      for (int i = 0; i < 4; ++i)
        p[rt * 4 + i] += acc[ct][rt][i] * ep[(size_t)i * DDIM];
    }
  }
#pragma unroll
  for (int off = 1; off < 16; off <<= 1)     // sum the 16 col-lanes per row
#pragma unroll
    for (int j = 0; j < 16; ++j)
      p[j] += __shfl_xor(p[j], off);
  if (l15 == 0) {
#pragma unroll
    for (int rt = 0; rt < 4; ++rt)
#pragma unroll
      for (int i = 0; i < 4; ++i)
        wsum[w][rt * 16 + quad * 4 + i] = p[rt * 4 + i];   // local row in half
  }
  __syncthreads();
  if (tid < 128) {
    int local = tid & 63, half = tid >> 6;
    float s = wsum[half * 2][local] + wsum[half * 2 + 1][local];
    atomicAdd(&out[m0 + tid], s);            // 8 d-tile blocks per output
  }
}

// ---- fallback (ws too small for eth_bf16): round-2 proven kernel ----
#define ETH_STRIDE 40
__global__ __launch_bounds__(256, 3) void bilinear_fp32eth(const float* __restrict__ elg,
                                                           const float* __restrict__ eth,
                                                           const unsigned short* __restrict__ Wb,
                                                           float* __restrict__ out) {
  __shared__ unsigned short ethL[64 * ETH_STRIDE];
  __shared__ unsigned short Wbuf[256 * 32];
  __shared__ float wsum[4][64];
  const int tid  = threadIdx.x;
  const int lane = tid & 63;
  const int w    = tid >> 6;
  const int quad = lane >> 4;
  const int l15  = lane & 15;
  const int m0   = (blockIdx.x >> 2) * 64;
  const int d0   = (blockIdx.x & 3) * 256;
  const int erow = tid >> 2, eunit = tid & 3;
  const float* esrc = eth + (size_t)(m0 + erow) * DDIM + eunit * 8;
  const int wr = lane >> 2, wu = lane & 3;
  float4v er0 = *(const float4v*)(esrc);
  float4v er1 = *(const float4v*)(esrc + 4);
  float4v acc[4][4];
#pragma unroll
  for (int ct = 0; ct < 4; ++ct)
#pragma unroll
    for (int rt = 0; rt < 4; ++rt)
      acc[ct][rt] = (float4v){0.f, 0.f, 0.f, 0.f};
  for (int ek = 0; ek < 32; ++ek) {
    const int e0 = ek * 32;
    __syncthreads();
    {
      uint4v pk;
      pk.x = pk2(er0.x, er0.y); pk.y = pk2(er0.z, er0.w);
      pk.z = pk2(er1.x, er1.y); pk.w = pk2(er1.z, er1.w);
      *(uint4v*)&ethL[erow * ETH_STRIDE + eunit * 8] = pk;
    }
#pragma unroll
    for (int j = 0; j < 4; ++j) {
      int r  = (w * 4 + j) * 16 + wr;
      int ug = wu ^ ((r >> 1) & 3);
      const unsigned short* gp = Wb + (size_t)(d0 + r) * DDIM + e0 + ug * 8;
      unsigned short* lp = &Wbuf[(w * 4 + j) * 512 + lane * 8];
      __builtin_amdgcn_global_load_lds(
          (const __attribute__((address_space(1))) unsigned int*)gp,
          (__attribute__((address_space(3))) unsigned int*)lp, 16, 0, 0);
    }
    __syncthreads();
    short8 aF[4], bF[4];
#pragma unroll
    for (int rt = 0; rt < 4; ++rt)
      aF[rt] = *(const short8*)&ethL[(rt * 16 + l15) * ETH_STRIDE + quad * 8];
#pragma unroll
    for (int ct = 0; ct < 4; ++ct) {
      int dl = w * 64 + ct * 16 + l15;
      int pu = quad ^ ((dl >> 1) & 3);
      bF[ct] = *(const short8*)&Wbuf[dl * 32 + pu * 8];
    }
    if (ek < 31) {
      const float* s = esrc + (e0 + 32);
      er0 = *(const float4v*)(s);
      er1 = *(const float4v*)(s + 4);
    }
#pragma unroll
    for (int ct = 0; ct < 4; ++ct)
#pragma unroll
      for (int rt = 0; rt < 4; ++rt)
        acc[ct][rt] = __builtin_amdgcn_mfma_f32_16x16x32_bf16(aF[rt], bF[ct], acc[ct][rt], 0, 0, 0);
  }
  float p[16];
#pragma unroll
  for (int j = 0; j < 16; ++j) p[j] = 0.f;
#pragma unroll
  for (int ct = 0; ct < 4; ++ct) {
    int col = d0 + w * 64 + ct * 16 + l15;
#pragma unroll
    for (int rt = 0; rt < 4; ++rt) {
      const float* ep = elg + (size_t)(m0 + rt * 16 + quad * 4) * DDIM + col;
#pragma unroll
      for (int i = 0; i < 4; ++i)
        p[rt * 4 + i] += acc[ct][rt][i] * ep[(size_t)i * DDIM];
    }
  }
#pragma unroll
  for (int off = 1; off < 16; off <<= 1)
#pragma unroll
    for (int j = 0; j < 16; ++j)
      p[j] += __shfl_xor(p[j], off);
  if (l15 == 0) {
#pragma unroll
    for (int rt = 0; rt < 4; ++rt)
#pragma unroll
      for (int i = 0; i < 4; ++i)
        wsum[w][rt * 16 + quad * 4 + i] = p[rt * 4 + i];
  }
  __syncthreads();
  if (tid < 64) {
    float s = wsum[0][tid] + wsum[1][tid] + wsum[2][tid] + wsum[3][tid];
    atomicAdd(&out[m0 + tid], s);
  }
}

extern "C" void kernel_launch(void* const* d_in, const int* in_sizes, int n_in,
                              void* d_out, int out_size, void* d_ws, size_t ws_size,
                              hipStream_t stream) {
  (void)in_sizes; (void)n_in;
  const float* elg = (const float*)d_in[0];
  const float* eth = (const float*)d_in[1];
  const float* W   = (const float*)d_in[2];
  float* out = (float*)d_out;
  unsigned short* Wb   = (unsigned short*)d_ws;                      // 2 MB
  unsigned short* ethB = (unsigned short*)((char*)d_ws + (2 << 20)); // 64 MB

  const size_t need = (2ull << 20) + (64ull << 20);
  hipMemsetAsync(d_out, 0, (size_t)out_size * sizeof(float), stream);
  if (ws_size >= need) {
    convert_all<<<dim3(512 + 16384), dim3(256), 0, stream>>>(W, eth, Wb, ethB);
    bilinear_bf16<<<dim3(2048), dim3(256), 0, stream>>>(elg, ethB, Wb, out);
  } else {
    convert_w<<<dim3(512), dim3(256), 0, stream>>>(W, Wb);
    bilinear_fp32eth<<<dim3(2048), dim3(256), 0, stream>>>(elg, eth, Wb, out);
  }
}

// Round 8
// 355.425 us; speedup vs baseline: 1.0331x; 1.0331x over previous
//
#include <hip/hip_runtime.h>
#include <hip/hip_bf16.h>

typedef __attribute__((ext_vector_type(8))) short short8;
typedef __attribute__((ext_vector_type(4))) float float4v;
typedef __attribute__((ext_vector_type(4))) unsigned int uint4v;

#define DDIM 1024

__device__ __forceinline__ unsigned short f2bf(float f) {
  unsigned u = __builtin_bit_cast(unsigned, f);
  unsigned r = (u + 0x7fffu + ((u >> 16) & 1u)) >> 16;   // RNE
  return (unsigned short)r;
}
__device__ __forceinline__ unsigned pk2(float lo, float hi) {
  return (unsigned)f2bf(lo) | ((unsigned)f2bf(hi) << 16);
}
__device__ __forceinline__ void cvt8(const float* src, unsigned short* dst) {
  float4v a = *(const float4v*)(src);
  float4v b = *(const float4v*)(src + 4);
  uint4v pk;
  pk.x = pk2(a.x, a.y); pk.y = pk2(a.z, a.w);
  pk.z = pk2(b.x, b.y); pk.w = pk2(b.z, b.w);
  *(uint4v*)dst = pk;
}

// ---- prepass: fp32 -> bf16, CHUNK-TRANSPOSED workspace ----
// Tile (g, ek) = 128 rows x 32 k stored as one contiguous 8 KB block
// [row][32k]: Wb[(dt*32+ek)*4096 + r*32 + k'], ethB[(mg*32+ek)*4096 + ...].
// Main-kernel stages then read 1 KB contiguous per wave-instr (full L2 lines)
// instead of 64 B segments at 2 KB stride (the round-6 L2-service wall).
// Convert reads: one full 128 B line per row per tile; writes: 8 KB contiguous.
__global__ __launch_bounds__(256) void convert_all(const float* __restrict__ W,
                                                   const float* __restrict__ eth,
                                                   unsigned short* __restrict__ Wb,
                                                   unsigned short* __restrict__ ethB) {
  const int b = blockIdx.x;
  const int t = threadIdx.x;
  const int r  = t >> 1;                    // row 0..127 in tile
  const int ku = t & 1;                     // 16-float half of the 32-k chunk
  if (b < 256) {                            // W tiles: (dt = b>>5, ek = b&31)
    const int dt = b >> 5, ek = b & 31;
    const float* src = W + (size_t)(dt * 128 + r) * DDIM + ek * 32 + ku * 16;
    unsigned short* dst = Wb + (size_t)b * 4096 + r * 32 + ku * 16;
    cvt8(src, dst);
    cvt8(src + 8, dst + 8);
  } else {                                  // eth tiles: (mg, ek)
    const int bb = b - 256;
    const int mg = bb >> 5, ek = bb & 31;
    const float* src = eth + (size_t)(mg * 128 + r) * DDIM + ek * 32 + ku * 16;
    unsigned short* dst = ethB + (size_t)bb * 4096 + r * 32 + ku * 16;
    cvt8(src, dst);
    cvt8(src + 8, dst + 8);
  }
}
// linear-layout W convert for the fallback path only
__global__ __launch_bounds__(256) void convert_w(const float* __restrict__ W,
                                                 unsigned short* __restrict__ Wb) {
  size_t i = ((size_t)blockIdx.x * 256 + threadIdx.x) * 8;
  cvt8(W + i, Wb + i);
}

// ---- main: 128 rows x 128 d-cols per block, K=1024 ----
// EXACT round-6 proven loop (2-buffer, 2-barrier, counted vmcnt(4), 104.5 us)
// -- rounds 6-7 proved the schedule shape is at its local optimum; the change
// here is purely the GLOBAL layout: chunk-transposed tiles make every DMA
// 1 KB contiguous (was 64 B @ 2 KB stride = half-line L2 sectors, measured
// 16.8 B/cyc/CU vs ~56 ceiling). LDS layout / swizzle / MFMA unchanged.
// XCD remap (verified FETCH 336->122 MB): mg=(b&7)|((b>>6)<<3), dt=(b>>3)&7.
__global__ __launch_bounds__(256, 4) void bilinear_bf16(const float* __restrict__ elg,
                                                        const unsigned short* __restrict__ ethB,
                                                        const unsigned short* __restrict__ Wb,
                                                        float* __restrict__ out) {
  __shared__ unsigned short Wbuf[2][128 * 32];  // 16 KB
  __shared__ unsigned short ethL[2][128 * 32];  // 16 KB
  __shared__ float wsum[4][64];                 // 1 KB

  const int tid  = threadIdx.x;
  const int lane = tid & 63;
  const int w    = tid >> 6;
  const int quad = lane >> 4;
  const int l15  = lane & 15;
  const int rowhalf = w >> 1;       // wave's 64-row half
  const int colhalf = w & 1;        // wave's 64-col half
  const int b  = blockIdx.x;
  const int mg = (b & 7) | ((b >> 6) << 3);   // m-group 0..255
  const int dt = (b >> 3) & 7;                // d-tile 0..7
  const int m0 = mg * 128;
  const int d0 = dt * 128;
  const int koff = ((b >> 8) & 3) * 8;        // K-phase stagger (neutral, kept)
  const int wr = lane >> 2, wu = lane & 3;    // DMA row/unit role

  // stage K-chunk ek into buffer buf: 4 DMA instrs/thread, 16 KB total.
  // Tile base is one contiguous 8 KB block; wave-instr j reads rows
  // R0..R0+15 = 1 KB contiguous (swizzle permutes inside each row's 64 B).
  auto stage = [&](int ek, int buf) {
    const unsigned short* gwt = Wb   + (size_t)(dt * 32 + ek) * 4096;
    const unsigned short* get = ethB + (size_t)(mg * 32 + ek) * 4096;
#pragma unroll
    for (int j = 0; j < 2; ++j) {
      const int R0 = w * 16 + j * 64;        // 16-row slab per wave-instr
      const int r  = R0 + wr;
      const int ug = wu ^ ((r >> 1) & 3);    // swizzle on the GLOBAL side
      const unsigned short* gw = gwt + r * 32 + ug * 8;
      const unsigned short* ge = get + r * 32 + ug * 8;
      unsigned short* lw = &Wbuf[buf][R0 * 32 + lane * 8];
      unsigned short* le = &ethL[buf][R0 * 32 + lane * 8];
      __builtin_amdgcn_global_load_lds(
          (const __attribute__((address_space(1))) unsigned int*)gw,
          (__attribute__((address_space(3))) unsigned int*)lw, 16, 0, 0);
      __builtin_amdgcn_global_load_lds(
          (const __attribute__((address_space(1))) unsigned int*)ge,
          (__attribute__((address_space(3))) unsigned int*)le, 16, 0, 0);
    }
  };

  float4v acc[4][4];
#pragma unroll
  for (int ct = 0; ct < 4; ++ct)
#pragma unroll
    for (int rt = 0; rt < 4; ++rt)
      acc[ct][rt] = (float4v){0.f, 0.f, 0.f, 0.f};

  // depth-2 prologue: chunks koff, koff+1 in flight (8 DMAs/thread outstanding)
  stage(koff, 0);
  stage((koff + 1) & 31, 1);

  for (int i = 0; i < 32; ++i) {
    const int cur = i & 1;
    // chunk i's 4 DMAs are the oldest outstanding; chunk i+1's stay in flight
    if (i < 31) asm volatile("s_waitcnt vmcnt(4)" ::: "memory");
    else        asm volatile("s_waitcnt vmcnt(0)" ::: "memory");
    __builtin_amdgcn_s_barrier();            // all waves: buf[cur] fully landed

    short8 aF[4], bF[4];
#pragma unroll
    for (int rt = 0; rt < 4; ++rt) {         // A[m=l15][k=quad*8+j]
      int r  = rowhalf * 64 + rt * 16 + l15;
      int pu = quad ^ ((r >> 1) & 3);
      aF[rt] = *(const short8*)&ethL[cur][r * 32 + pu * 8];
    }
#pragma unroll
    for (int ct = 0; ct < 4; ++ct) {         // B[k][n=l15] = W row d
      int r  = colhalf * 64 + ct * 16 + l15;
      int pu = quad ^ ((r >> 1) & 3);
      bF[ct] = *(const short8*)&Wbuf[cur][r * 32 + pu * 8];
    }
    asm volatile("s_waitcnt lgkmcnt(0)" ::: "memory");  // my reads of buf[cur] retired
    __builtin_amdgcn_s_barrier();            // all waves' reads retired -> cur free
    if (i < 30) stage((i + 2 + koff) & 31, cur);  // refill cur; overlaps MFMA

    __builtin_amdgcn_s_setprio(1);
#pragma unroll
    for (int ct = 0; ct < 4; ++ct)
#pragma unroll
      for (int rt = 0; rt < 4; ++rt)
        acc[ct][rt] = __builtin_amdgcn_mfma_f32_16x16x32_bf16(aF[rt], bF[ct], acc[ct][rt], 0, 0, 0);
    __builtin_amdgcn_s_setprio(0);
  }

  // fused epilogue: p[m] = sum_col elg[m][col] * u[m][col] over this d-tile
  float p[16];
#pragma unroll
  for (int j = 0; j < 16; ++j) p[j] = 0.f;
#pragma unroll
  for (int ct = 0; ct < 4; ++ct) {
    int col = d0 + colhalf * 64 + ct * 16 + l15;
#pragma unroll
    for (int rt = 0; rt < 4; ++rt) {
      const float* ep = elg + (size_t)(m0 + rowhalf * 64 + rt * 16 + quad * 4) * DDIM + col;
#pragma unroll
      for (int i = 0; i < 4; ++i)
        p[rt * 4 + i] += acc[ct][rt][i] * ep[(size_t)i * DDIM];
    }
  }
#pragma unroll
  for (int off = 1; off < 16; off <<= 1)     // sum the 16 col-lanes per row
#pragma unroll
    for (int j = 0; j < 16; ++j)
      p[j] += __shfl_xor(p[j], off);
  if (l15 == 0) {
#pragma unroll
    for (int rt = 0; rt < 4; ++rt)
#pragma unroll
      for (int i = 0; i < 4; ++i)
        wsum[w][rt * 16 + quad * 4 + i] = p[rt * 4 + i];   // local row in half
  }
  __syncthreads();
  if (tid < 128) {
    int local = tid & 63, half = tid >> 6;
    float s = wsum[half * 2][local] + wsum[half * 2 + 1][local];
    atomicAdd(&out[m0 + tid], s);            // 8 d-tile blocks per output
  }
}

// ---- fallback (ws too small for eth_bf16): round-2 proven kernel ----
// Uses LINEAR Wb layout (written by convert_w).
#define ETH_STRIDE 40
__global__ __launch_bounds__(256, 3) void bilinear_fp32eth(const float* __restrict__ elg,
                                                           const float* __restrict__ eth,
                                                           const unsigned short* __restrict__ Wb,
                                                           float* __restrict__ out) {
  __shared__ unsigned short ethL[64 * ETH_STRIDE];
  __shared__ unsigned short Wbuf[256 * 32];
  __shared__ float wsum[4][64];
  const int tid  = threadIdx.x;
  const int lane = tid & 63;
  const int w    = tid >> 6;
  const int quad = lane >> 4;
  const int l15  = lane & 15;
  const int m0   = (blockIdx.x >> 2) * 64;
  const int d0   = (blockIdx.x & 3) * 256;
  const int erow = tid >> 2, eunit = tid & 3;
  const float* esrc = eth + (size_t)(m0 + erow) * DDIM + eunit * 8;
  const int wr = lane >> 2, wu = lane & 3;
  float4v er0 = *(const float4v*)(esrc);
  float4v er1 = *(const float4v*)(esrc + 4);
  float4v acc[4][4];
#pragma unroll
  for (int ct = 0; ct < 4; ++ct)
#pragma unroll
    for (int rt = 0; rt < 4; ++rt)
      acc[ct][rt] = (float4v){0.f, 0.f, 0.f, 0.f};
  for (int ek = 0; ek < 32; ++ek) {
    const int e0 = ek * 32;
    __syncthreads();
    {
      uint4v pk;
      pk.x = pk2(er0.x, er0.y); pk.y = pk2(er0.z, er0.w);
      pk.z = pk2(er1.x, er1.y); pk.w = pk2(er1.z, er1.w);
      *(uint4v*)&ethL[erow * ETH_STRIDE + eunit * 8] = pk;
    }
#pragma unroll
    for (int j = 0; j < 4; ++j) {
      int r  = (w * 4 + j) * 16 + wr;
      int ug = wu ^ ((r >> 1) & 3);
      const unsigned short* gp = Wb + (size_t)(d0 + r) * DDIM + e0 + ug * 8;
      unsigned short* lp = &Wbuf[(w * 4 + j) * 512 + lane * 8];
      __builtin_amdgcn_global_load_lds(
          (const __attribute__((address_space(1))) unsigned int*)gp,
          (__attribute__((address_space(3))) unsigned int*)lp, 16, 0, 0);
    }
    __syncthreads();
    short8 aF[4], bF[4];
#pragma unroll
    for (int rt = 0; rt < 4; ++rt)
      aF[rt] = *(const short8*)&ethL[(rt * 16 + l15) * ETH_STRIDE + quad * 8];
#pragma unroll
    for (int ct = 0; ct < 4; ++ct) {
      int dl = w * 64 + ct * 16 + l15;
      int pu = quad ^ ((dl >> 1) & 3);
      bF[ct] = *(const short8*)&Wbuf[dl * 32 + pu * 8];
    }
    if (ek < 31) {
      const float* s = esrc + (e0 + 32);
      er0 = *(const float4v*)(s);
      er1 = *(const float4v*)(s + 4);
    }
#pragma unroll
    for (int ct = 0; ct < 4; ++ct)
#pragma unroll
      for (int rt = 0; rt < 4; ++rt)
        acc[ct][rt] = __builtin_amdgcn_mfma_f32_16x16x32_bf16(aF[rt], bF[ct], acc[ct][rt], 0, 0, 0);
  }
  float p[16];
#pragma unroll
  for (int j = 0; j < 16; ++j) p[j] = 0.f;
#pragma unroll
  for (int ct = 0; ct < 4; ++ct) {
    int col = d0 + w * 64 + ct * 16 + l15;
#pragma unroll
    for (int rt = 0; rt < 4; ++rt) {
      const float* ep = elg + (size_t)(m0 + rt * 16 + quad * 4) * DDIM + col;
#pragma unroll
      for (int i = 0; i < 4; ++i)
        p[rt * 4 + i] += acc[ct][rt][i] * ep[(size_t)i * DDIM];
    }
  }
#pragma unroll
  for (int off = 1; off < 16; off <<= 1)
#pragma unroll
    for (int j = 0; j < 16; ++j)
      p[j] += __shfl_xor(p[j], off);
  if (l15 == 0) {
#pragma unroll
    for (int rt = 0; rt < 4; ++rt)
#pragma unroll
      for (int i = 0; i < 4; ++i)
        wsum[w][rt * 16 + quad * 4 + i] = p[rt * 4 + i];
  }
  __syncthreads();
  if (tid < 64) {
    float s = wsum[0][tid] + wsum[1][tid] + wsum[2][tid] + wsum[3][tid];
    atomicAdd(&out[m0 + tid], s);
  }
}

extern "C" void kernel_launch(void* const* d_in, const int* in_sizes, int n_in,
                              void* d_out, int out_size, void* d_ws, size_t ws_size,
                              hipStream_t stream) {
  (void)in_sizes; (void)n_in;
  const float* elg = (const float*)d_in[0];
  const float* eth = (const float*)d_in[1];
  const float* W   = (const float*)d_in[2];
  float* out = (float*)d_out;
  unsigned short* Wb   = (unsigned short*)d_ws;                      // 2 MB
  unsigned short* ethB = (unsigned short*)((char*)d_ws + (2 << 20)); // 64 MB

  const size_t need = (2ull << 20) + (64ull << 20);
  hipMemsetAsync(d_out, 0, (size_t)out_size * sizeof(float), stream);
  if (ws_size >= need) {
    convert_all<<<dim3(256 + 8192), dim3(256), 0, stream>>>(W, eth, Wb, ethB);
    bilinear_bf16<<<dim3(2048), dim3(256), 0, stream>>>(elg, ethB, Wb, out);
  } else {
    convert_w<<<dim3(512), dim3(256), 0, stream>>>(W, Wb);
    bilinear_fp32eth<<<dim3(2048), dim3(256), 0, stream>>>(elg, eth, Wb, out);
  }
}

// Round 9
// 331.027 us; speedup vs baseline: 1.1092x; 1.0737x over previous
//
#include <hip/hip_runtime.h>
#include <hip/hip_bf16.h>

typedef __attribute__((ext_vector_type(8))) short short8;
typedef __attribute__((ext_vector_type(4))) float float4v;
typedef __attribute__((ext_vector_type(4))) unsigned int uint4v;

#define DDIM 1024

__device__ __forceinline__ unsigned short f2bf(float f) {
  unsigned u = __builtin_bit_cast(unsigned, f);
  unsigned r = (u + 0x7fffu + ((u >> 16) & 1u)) >> 16;   // RNE
  return (unsigned short)r;
}
__device__ __forceinline__ unsigned pk2(float lo, float hi) {
  return (unsigned)f2bf(lo) | ((unsigned)f2bf(hi) << 16);
}
__device__ __forceinline__ void cvt8(const float* src, unsigned short* dst) {
  float4v a = *(const float4v*)(src);
  float4v b = *(const float4v*)(src + 4);
  uint4v pk;
  pk.x = pk2(a.x, a.y); pk.y = pk2(a.z, a.w);
  pk.z = pk2(b.x, b.y); pk.w = pk2(b.z, b.w);
  *(uint4v*)dst = pk;
}

// ---- prepass: fp32 -> bf16 into CHUNK-TRANSPOSED workspace ----
// Workspace layout (consumed by bilinear_bf16, unchanged from round 8):
//   tile (g, ek) = one contiguous 8 KB block [128 r][32 k]:
//   Wb[(dt*32+ek)*4096 + r*32 + k], ethB[(mg*32+ek)*4096 + r*32 + k].
// Round 9: LINEAR READS restored (round-8 convert read one 128 B line per row
// at 4 KB stride -> 2.05 TB/s, 92 us). Each thread converts 2x8 consecutive
// floats (fully coalesced read stream, two independent chains for ILP) and
// scatters 16 B units to the transposed position. The two 64 B halves of each
// output line are written by waves of the same block within a short window ->
// write-back L2 merges them.
__global__ __launch_bounds__(256) void convert_all(const float* __restrict__ W,
                                                   const float* __restrict__ eth,
                                                   unsigned short* __restrict__ Wb,
                                                   unsigned short* __restrict__ ethB) {
  const int b = blockIdx.x;
  const int t = threadIdx.x;
  if (b < 256) {                             // W: units 0 .. 131071 (1M floats)
    size_t u0 = (size_t)b * 512 + t;
#pragma unroll
    for (int j = 0; j < 2; ++j) {
      size_t i = u0 + (size_t)j * 256;       // 8-float unit index
      int row = (int)(i >> 7);               // source row 0..1023
      int u   = (int)(i & 127);              // 8-float unit within row
      int dt = row >> 7, r = row & 127;
      int ek = u >> 2,  ku = u & 3;
      cvt8(W + i * 8,
           Wb + ((size_t)(dt * 32 + ek)) * 4096 + r * 32 + ku * 8);
    }
  } else {                                   // eth: 32M floats
    size_t u0 = (size_t)(b - 256) * 512 + t;
#pragma unroll
    for (int j = 0; j < 2; ++j) {
      size_t i = u0 + (size_t)j * 256;
      int row = (int)(i >> 7);               // source row 0..32767
      int u   = (int)(i & 127);
      int mg = row >> 7, r = row & 127;
      int ek = u >> 2,  ku = u & 3;
      cvt8(eth + i * 8,
           ethB + ((size_t)(mg * 32 + ek)) * 4096 + r * 32 + ku * 8);
    }
  }
}
// linear-layout W convert for the fallback path only
__global__ __launch_bounds__(256) void convert_w(const float* __restrict__ W,
                                                 unsigned short* __restrict__ Wb) {
  size_t i = ((size_t)blockIdx.x * 256 + threadIdx.x) * 8;
  cvt8(W + i, Wb + i);
}

// ---- main: 128 rows x 128 d-cols per block, K=1024 ----
// FROZEN round-8 kernel (91 us): 2-buffer 2-barrier counted-vmcnt loop +
// chunk-transposed tiles (every DMA 1 KB contiguous; was 64 B @ 2 KB stride).
// XCD remap (verified FETCH 336->122 MB): mg=(b&7)|((b>>6)<<3), dt=(b>>3)&7.
__global__ __launch_bounds__(256, 4) void bilinear_bf16(const float* __restrict__ elg,
                                                        const unsigned short* __restrict__ ethB,
                                                        const unsigned short* __restrict__ Wb,
                                                        float* __restrict__ out) {
  __shared__ unsigned short Wbuf[2][128 * 32];  // 16 KB
  __shared__ unsigned short ethL[2][128 * 32];  // 16 KB
  __shared__ float wsum[4][64];                 // 1 KB

  const int tid  = threadIdx.x;
  const int lane = tid & 63;
  const int w    = tid >> 6;
  const int quad = lane >> 4;
  const int l15  = lane & 15;
  const int rowhalf = w >> 1;       // wave's 64-row half
  const int colhalf = w & 1;        // wave's 64-col half
  const int b  = blockIdx.x;
  const int mg = (b & 7) | ((b >> 6) << 3);   // m-group 0..255
  const int dt = (b >> 3) & 7;                // d-tile 0..7
  const int m0 = mg * 128;
  const int d0 = dt * 128;
  const int koff = ((b >> 8) & 3) * 8;        // K-phase stagger (neutral, kept)
  const int wr = lane >> 2, wu = lane & 3;    // DMA row/unit role

  // stage K-chunk ek into buffer buf: 4 DMA instrs/thread, 16 KB total.
  // Tile base is one contiguous 8 KB block; wave-instr j reads rows
  // R0..R0+15 = 1 KB contiguous (swizzle permutes inside each row's 64 B).
  auto stage = [&](int ek, int buf) {
    const unsigned short* gwt = Wb   + (size_t)(dt * 32 + ek) * 4096;
    const unsigned short* get = ethB + (size_t)(mg * 32 + ek) * 4096;
#pragma unroll
    for (int j = 0; j < 2; ++j) {
      const int R0 = w * 16 + j * 64;        // 16-row slab per wave-instr
      const int r  = R0 + wr;
      const int ug = wu ^ ((r >> 1) & 3);    // swizzle on the GLOBAL side
      const unsigned short* gw = gwt + r * 32 + ug * 8;
      const unsigned short* ge = get + r * 32 + ug * 8;
      unsigned short* lw = &Wbuf[buf][R0 * 32 + lane * 8];
      unsigned short* le = &ethL[buf][R0 * 32 + lane * 8];
      __builtin_amdgcn_global_load_lds(
          (const __attribute__((address_space(1))) unsigned int*)gw,
          (__attribute__((address_space(3))) unsigned int*)lw, 16, 0, 0);
      __builtin_amdgcn_global_load_lds(
          (const __attribute__((address_space(1))) unsigned int*)ge,
          (__attribute__((address_space(3))) unsigned int*)le, 16, 0, 0);
    }
  };

  float4v acc[4][4];
#pragma unroll
  for (int ct = 0; ct < 4; ++ct)
#pragma unroll
    for (int rt = 0; rt < 4; ++rt)
      acc[ct][rt] = (float4v){0.f, 0.f, 0.f, 0.f};

  // depth-2 prologue: chunks koff, koff+1 in flight (8 DMAs/thread outstanding)
  stage(koff, 0);
  stage((koff + 1) & 31, 1);

  for (int i = 0; i < 32; ++i) {
    const int cur = i & 1;
    // chunk i's 4 DMAs are the oldest outstanding; chunk i+1's stay in flight
    if (i < 31) asm volatile("s_waitcnt vmcnt(4)" ::: "memory");
    else        asm volatile("s_waitcnt vmcnt(0)" ::: "memory");
    __builtin_amdgcn_s_barrier();            // all waves: buf[cur] fully landed

    short8 aF[4], bF[4];
#pragma unroll
    for (int rt = 0; rt < 4; ++rt) {         // A[m=l15][k=quad*8+j]
      int r  = rowhalf * 64 + rt * 16 + l15;
      int pu = quad ^ ((r >> 1) & 3);
      aF[rt] = *(const short8*)&ethL[cur][r * 32 + pu * 8];
    }
#pragma unroll
    for (int ct = 0; ct < 4; ++ct) {         // B[k][n=l15] = W row d
      int r  = colhalf * 64 + ct * 16 + l15;
      int pu = quad ^ ((r >> 1) & 3);
      bF[ct] = *(const short8*)&Wbuf[cur][r * 32 + pu * 8];
    }
    asm volatile("s_waitcnt lgkmcnt(0)" ::: "memory");  // my reads of buf[cur] retired
    __builtin_amdgcn_s_barrier();            // all waves' reads retired -> cur free
    if (i < 30) stage((i + 2 + koff) & 31, cur);  // refill cur; overlaps MFMA

    __builtin_amdgcn_s_setprio(1);
#pragma unroll
    for (int ct = 0; ct < 4; ++ct)
#pragma unroll
      for (int rt = 0; rt < 4; ++rt)
        acc[ct][rt] = __builtin_amdgcn_mfma_f32_16x16x32_bf16(aF[rt], bF[ct], acc[ct][rt], 0, 0, 0);
    __builtin_amdgcn_s_setprio(0);
  }

  // fused epilogue: p[m] = sum_col elg[m][col] * u[m][col] over this d-tile
  float p[16];
#pragma unroll
  for (int j = 0; j < 16; ++j) p[j] = 0.f;
#pragma unroll
  for (int ct = 0; ct < 4; ++ct) {
    int col = d0 + colhalf * 64 + ct * 16 + l15;
#pragma unroll
    for (int rt = 0; rt < 4; ++rt) {
      const float* ep = elg + (size_t)(m0 + rowhalf * 64 + rt * 16 + quad * 4) * DDIM + col;
#pragma unroll
      for (int i = 0; i < 4; ++i)
        p[rt * 4 + i] += acc[ct][rt][i] * ep[(size_t)i * DDIM];
    }
  }
#pragma unroll
  for (int off = 1; off < 16; off <<= 1)     // sum the 16 col-lanes per row
#pragma unroll
    for (int j = 0; j < 16; ++j)
      p[j] += __shfl_xor(p[j], off);
  if (l15 == 0) {
#pragma unroll
    for (int rt = 0; rt < 4; ++rt)
#pragma unroll
      for (int i = 0; i < 4; ++i)
        wsum[w][rt * 16 + quad * 4 + i] = p[rt * 4 + i];   // local row in half
  }
  __syncthreads();
  if (tid < 128) {
    int local = tid & 63, half = tid >> 6;
    float s = wsum[half * 2][local] + wsum[half * 2 + 1][local];
    atomicAdd(&out[m0 + tid], s);            // 8 d-tile blocks per output
  }
}

// ---- fallback (ws too small for eth_bf16): round-2 proven kernel ----
// Uses LINEAR Wb layout (written by convert_w).
#define ETH_STRIDE 40
__global__ __launch_bounds__(256, 3) void bilinear_fp32eth(const float* __restrict__ elg,
                                                           const float* __restrict__ eth,
                                                           const unsigned short* __restrict__ Wb,
                                                           float* __restrict__ out) {
  __shared__ unsigned short ethL[64 * ETH_STRIDE];
  __shared__ unsigned short Wbuf[256 * 32];
  __shared__ float wsum[4][64];
  const int tid  = threadIdx.x;
  const int lane = tid & 63;
  const int w    = tid >> 6;
  const int quad = lane >> 4;
  const int l15  = lane & 15;
  const int m0   = (blockIdx.x >> 2) * 64;
  const int d0   = (blockIdx.x & 3) * 256;
  const int erow = tid >> 2, eunit = tid & 3;
  const float* esrc = eth + (size_t)(m0 + erow) * DDIM + eunit * 8;
  const int wr = lane >> 2, wu = lane & 3;
  float4v er0 = *(const float4v*)(esrc);
  float4v er1 = *(const float4v*)(esrc + 4);
  float4v acc[4][4];
#pragma unroll
  for (int ct = 0; ct < 4; ++ct)
#pragma unroll
    for (int rt = 0; rt < 4; ++rt)
      acc[ct][rt] = (float4v){0.f, 0.f, 0.f, 0.f};
  for (int ek = 0; ek < 32; ++ek) {
    const int e0 = ek * 32;
    __syncthreads();
    {
      uint4v pk;
      pk.x = pk2(er0.x, er0.y); pk.y = pk2(er0.z, er0.w);
      pk.z = pk2(er1.x, er1.y); pk.w = pk2(er1.z, er1.w);
      *(uint4v*)&ethL[erow * ETH_STRIDE + eunit * 8] = pk;
    }
#pragma unroll
    for (int j = 0; j < 4; ++j) {
      int r  = (w * 4 + j) * 16 + wr;
      int ug = wu ^ ((r >> 1) & 3);
      const unsigned short* gp = Wb + (size_t)(d0 + r) * DDIM + e0 + ug * 8;
      unsigned short* lp = &Wbuf[(w * 4 + j) * 512 + lane * 8];
      __builtin_amdgcn_global_load_lds(
          (const __attribute__((address_space(1))) unsigned int*)gp,
          (__attribute__((address_space(3))) unsigned int*)lp, 16, 0, 0);
    }
    __syncthreads();
    short8 aF[4], bF[4];
#pragma unroll
    for (int rt = 0; rt < 4; ++rt)
      aF[rt] = *(const short8*)&ethL[(rt * 16 + l15) * ETH_STRIDE + quad * 8];
#pragma unroll
    for (int ct = 0; ct < 4; ++ct) {
      int dl = w * 64 + ct * 16 + l15;
      int pu = quad ^ ((dl >> 1) & 3);
      bF[ct] = *(const short8*)&Wbuf[dl * 32 + pu * 8];
    }
    if (ek < 31) {
      const float* s = esrc + (e0 + 32);
      er0 = *(const float4v*)(s);
      er1 = *(const float4v*)(s + 4);
    }
#pragma unroll
    for (int ct = 0; ct < 4; ++ct)
#pragma unroll
      for (int rt = 0; rt < 4; ++rt)
        acc[ct][rt] = __builtin_amdgcn_mfma_f32_16x16x32_bf16(aF[rt], bF[ct], acc[ct][rt], 0, 0, 0);
  }
  float p[16];
#pragma unroll
  for (int j = 0; j < 16; ++j) p[j] = 0.f;
#pragma unroll
  for (int ct = 0; ct < 4; ++ct) {
    int col = d0 + w * 64 + ct * 16 + l15;
#pragma unroll
    for (int rt = 0; rt < 4; ++rt) {
      const float* ep = elg + (size_t)(m0 + rt * 16 + quad * 4) * DDIM + col;
#pragma unroll
      for (int i = 0; i < 4; ++i)
        p[rt * 4 + i] += acc[ct][rt][i] * ep[(size_t)i * DDIM];
    }
  }
#pragma unroll
  for (int off = 1; off < 16; off <<= 1)
#pragma unroll
    for (int j = 0; j < 16; ++j)
      p[j] += __shfl_xor(p[j], off);
  if (l15 == 0) {
#pragma unroll
    for (int rt = 0; rt < 4; ++rt)
#pragma unroll
      for (int i = 0; i < 4; ++i)
        wsum[w][rt * 16 + quad * 4 + i] = p[rt * 4 + i];
  }
  __syncthreads();
  if (tid < 64) {
    float s = wsum[0][tid] + wsum[1][tid] + wsum[2][tid] + wsum[3][tid];
    atomicAdd(&out[m0 + tid], s);
  }
}

extern "C" void kernel_launch(void* const* d_in, const int* in_sizes, int n_in,
                              void* d_out, int out_size, void* d_ws, size_t ws_size,
                              hipStream_t stream) {
  (void)in_sizes; (void)n_in;
  const float* elg = (const float*)d_in[0];
  const float* eth = (const float*)d_in[1];
  const float* W   = (const float*)d_in[2];
  float* out = (float*)d_out;
  unsigned short* Wb   = (unsigned short*)d_ws;                      // 2 MB
  unsigned short* ethB = (unsigned short*)((char*)d_ws + (2 << 20)); // 64 MB

  const size_t need = (2ull << 20) + (64ull << 20);
  hipMemsetAsync(d_out, 0, (size_t)out_size * sizeof(float), stream);
  if (ws_size >= need) {
    convert_all<<<dim3(256 + 8192), dim3(256), 0, stream>>>(W, eth, Wb, ethB);
    bilinear_bf16<<<dim3(2048), dim3(256), 0, stream>>>(elg, ethB, Wb, out);
  } else {
    convert_w<<<dim3(512), dim3(256), 0, stream>>>(W, Wb);
    bilinear_fp32eth<<<dim3(2048), dim3(256), 0, stream>>>(elg, eth, Wb, out);
  }
}

// Round 10
// 323.276 us; speedup vs baseline: 1.1358x; 1.0240x over previous
//
#include <hip/hip_runtime.h>
#include <hip/hip_bf16.h>

typedef __attribute__((ext_vector_type(8))) short short8;
typedef __attribute__((ext_vector_type(4))) float float4v;
typedef __attribute__((ext_vector_type(4))) unsigned int uint4v;

#define DDIM 1024

__device__ __forceinline__ unsigned short f2bf(float f) {
  unsigned u = __builtin_bit_cast(unsigned, f);
  unsigned r = (u + 0x7fffu + ((u >> 16) & 1u)) >> 16;   // RNE
  return (unsigned short)r;
}
__device__ __forceinline__ unsigned pk2(float lo, float hi) {
  return (unsigned)f2bf(lo) | ((unsigned)f2bf(hi) << 16);
}
__device__ __forceinline__ void cvt8(const float* src, unsigned short* dst) {
  float4v a = *(const float4v*)(src);
  float4v b = *(const float4v*)(src + 4);
  uint4v pk;
  pk.x = pk2(a.x, a.y); pk.y = pk2(a.z, a.w);
  pk.z = pk2(b.x, b.y); pk.w = pk2(b.z, b.w);
  *(uint4v*)dst = pk;
}

// ---- prepass: fp32 -> bf16 into CHUNK-TRANSPOSED workspace (round-9 proven) ----
// tile (g, ek) = one contiguous 8 KB block [128 r][32 k]:
//   Wb[(dt*32+ek)*4096 + r*32 + k], ethB[(g*32+ek)*4096 + r*32 + k], g = row>>7.
// Linear coalesced reads; 16 B write units scattered to transposed positions.
__global__ __launch_bounds__(256) void convert_all(const float* __restrict__ W,
                                                   const float* __restrict__ eth,
                                                   unsigned short* __restrict__ Wb,
                                                   unsigned short* __restrict__ ethB) {
  const int b = blockIdx.x;
  const int t = threadIdx.x;
  if (b < 256) {                             // W: 1M floats
    size_t u0 = (size_t)b * 512 + t;
#pragma unroll
    for (int j = 0; j < 2; ++j) {
      size_t i = u0 + (size_t)j * 256;
      int row = (int)(i >> 7);
      int u   = (int)(i & 127);
      int dt = row >> 7, r = row & 127;
      int ek = u >> 2,  ku = u & 3;
      cvt8(W + i * 8,
           Wb + ((size_t)(dt * 32 + ek)) * 4096 + r * 32 + ku * 8);
    }
  } else {                                   // eth: 32M floats
    size_t u0 = (size_t)(b - 256) * 512 + t;
#pragma unroll
    for (int j = 0; j < 2; ++j) {
      size_t i = u0 + (size_t)j * 256;
      int row = (int)(i >> 7);
      int u   = (int)(i & 127);
      int mg = row >> 7, r = row & 127;
      int ek = u >> 2,  ku = u & 3;
      cvt8(eth + i * 8,
           ethB + ((size_t)(mg * 32 + ek)) * 4096 + r * 32 + ku * 8);
    }
  }
}
// linear-layout W convert for the fallback path only
__global__ __launch_bounds__(256) void convert_w(const float* __restrict__ W,
                                                 unsigned short* __restrict__ Wb) {
  size_t i = ((size_t)blockIdx.x * 256 + threadIdx.x) * 8;
  cvt8(W + i, Wb + i);
}

// ---- main: 256 rows x 128 d-cols per block, 512 threads (8 waves), K=1024 ----
// Round 10: TILE GROWTH. Round 9 showed the kernel is L2-BW-bound per CU
// (3 blocks x 16 KB / 830 cyc = 58 B/cyc = the ~56 B/cyc L2 ceiling), so the
// lever is arithmetic intensity: (1/BM+1/BD) drops 0.75x with BM=256.
// Per-wave inner loop is IDENTICAL to the round-9 proven kernel (64x64 output,
// 4x4 fragments, 64 AGPR acc, same swizzle, 2-barrier counted-vmcnt loop);
// staging is 3 DMA instrs/thread (eth 2 + W 1) -> vmcnt(3).
// Wave w: row-group wr2=w>>1 (4 x 64 rows), col-half wc2=w&1 (2 x 64 cols).
// LDS 50 KB, launch_bounds(512,4) caps 128 regs/wave (= proven 64V+64A)
// -> 2 blocks/CU = 16 waves. XCD remap: the 8 dt blocks of an mg share b&7.
__global__ __launch_bounds__(512, 4) void bilinear_bf16(const float* __restrict__ elg,
                                                        const unsigned short* __restrict__ ethB,
                                                        const unsigned short* __restrict__ Wb,
                                                        float* __restrict__ out) {
  __shared__ unsigned short ethL[2][256 * 32];  // 32 KB
  __shared__ unsigned short Wbuf[2][128 * 32];  // 16 KB
  __shared__ float wsum[8][64];                 // 2 KB

  const int tid  = threadIdx.x;
  const int lane = tid & 63;
  const int w    = tid >> 6;        // 0..7
  const int quad = lane >> 4;
  const int l15  = lane & 15;
  const int wr2 = w >> 1;           // wave's 64-row group (0..3)
  const int wc2 = w & 1;            // wave's 64-col half (0..1)
  const int b  = blockIdx.x;
  const int mg = (b & 7) | ((b >> 6) << 3);   // m-group 0..127 (256 rows each)
  const int dt = (b >> 3) & 7;                // d-tile 0..7
  const int m0 = mg * 256;
  const int d0 = dt * 128;
  const int koff = ((b >> 8) & 3) * 8;        // K-phase stagger (neutral, kept)
  const int wr = lane >> 2, wu = lane & 3;    // DMA row/unit role

  // stage K-chunk ek: 3 DMA instrs/thread (eth 2 + W 1), 24 KB total.
  auto stage = [&](int ek, int buf) {
    const unsigned short* gwt = Wb + (size_t)(dt * 32 + ek) * 4096;
#pragma unroll
    for (int j = 0; j < 2; ++j) {            // eth rows w*32 .. w*32+31
      const int R0 = w * 32 + j * 16;
      const int r  = R0 + wr;                // 0..255
      const int ug = wu ^ ((r >> 1) & 3);    // swizzle on the GLOBAL side
      const int sub = r >> 7, rr = r & 127;  // 128-row convert subtile
      const unsigned short* ge = ethB
          + (size_t)((2 * mg + sub) * 32 + ek) * 4096 + rr * 32 + ug * 8;
      unsigned short* le = &ethL[buf][R0 * 32 + lane * 8];
      __builtin_amdgcn_global_load_lds(
          (const __attribute__((address_space(1))) unsigned int*)ge,
          (__attribute__((address_space(3))) unsigned int*)le, 16, 0, 0);
    }
    {                                        // W rows w*16 .. w*16+15
      const int R0 = w * 16;
      const int r  = R0 + wr;                // 0..127
      const int ug = wu ^ ((r >> 1) & 3);
      const unsigned short* gw = gwt + r * 32 + ug * 8;
      unsigned short* lw = &Wbuf[buf][R0 * 32 + lane * 8];
      __builtin_amdgcn_global_load_lds(
          (const __attribute__((address_space(1))) unsigned int*)gw,
          (__attribute__((address_space(3))) unsigned int*)lw, 16, 0, 0);
    }
  };

  float4v acc[4][4];
#pragma unroll
  for (int ct = 0; ct < 4; ++ct)
#pragma unroll
    for (int rt = 0; rt < 4; ++rt)
      acc[ct][rt] = (float4v){0.f, 0.f, 0.f, 0.f};

  // depth-2 prologue: chunks koff, koff+1 in flight (6 DMAs/thread outstanding)
  stage(koff, 0);
  stage((koff + 1) & 31, 1);

  for (int i = 0; i < 32; ++i) {
    const int cur = i & 1;
    // chunk i's 3 DMAs are the oldest outstanding; chunk i+1's stay in flight
    if (i < 31) asm volatile("s_waitcnt vmcnt(3)" ::: "memory");
    else        asm volatile("s_waitcnt vmcnt(0)" ::: "memory");
    __builtin_amdgcn_s_barrier();            // all waves: buf[cur] fully landed

    short8 aF[4], bF[4];
#pragma unroll
    for (int rt = 0; rt < 4; ++rt) {         // A[m=l15][k=quad*8+j]
      int r  = wr2 * 64 + rt * 16 + l15;     // 0..255
      int pu = quad ^ ((r >> 1) & 3);
      aF[rt] = *(const short8*)&ethL[cur][r * 32 + pu * 8];
    }
#pragma unroll
    for (int ct = 0; ct < 4; ++ct) {         // B[k][n=l15] = W row d
      int r  = wc2 * 64 + ct * 16 + l15;     // 0..127
      int pu = quad ^ ((r >> 1) & 3);
      bF[ct] = *(const short8*)&Wbuf[cur][r * 32 + pu * 8];
    }
    asm volatile("s_waitcnt lgkmcnt(0)" ::: "memory");  // my reads retired
    __builtin_amdgcn_s_barrier();            // all waves' reads retired -> cur free
    if (i < 30) stage((i + 2 + koff) & 31, cur);  // refill cur; overlaps MFMA

    __builtin_amdgcn_s_setprio(1);
#pragma unroll
    for (int ct = 0; ct < 4; ++ct)
#pragma unroll
      for (int rt = 0; rt < 4; ++rt)
        acc[ct][rt] = __builtin_amdgcn_mfma_f32_16x16x32_bf16(aF[rt], bF[ct], acc[ct][rt], 0, 0, 0);
    __builtin_amdgcn_s_setprio(0);
  }

  // fused epilogue: p[m] = sum_col elg[m][col] * u[m][col] over this d-tile
  float p[16];
#pragma unroll
  for (int j = 0; j < 16; ++j) p[j] = 0.f;
#pragma unroll
  for (int ct = 0; ct < 4; ++ct) {
    int col = d0 + wc2 * 64 + ct * 16 + l15;
#pragma unroll
    for (int rt = 0; rt < 4; ++rt) {
      const float* ep = elg + (size_t)(m0 + wr2 * 64 + rt * 16 + quad * 4) * DDIM + col;
#pragma unroll
      for (int i = 0; i < 4; ++i)
        p[rt * 4 + i] += acc[ct][rt][i] * ep[(size_t)i * DDIM];
    }
  }
#pragma unroll
  for (int off = 1; off < 16; off <<= 1)     // sum the 16 col-lanes per row
#pragma unroll
    for (int j = 0; j < 16; ++j)
      p[j] += __shfl_xor(p[j], off);
  if (l15 == 0) {
#pragma unroll
    for (int rt = 0; rt < 4; ++rt)
#pragma unroll
      for (int i = 0; i < 4; ++i)
        wsum[w][rt * 16 + quad * 4 + i] = p[rt * 4 + i];   // local row in 64-group
  }
  __syncthreads();
  if (tid < 256) {
    int rg = tid >> 6, local = tid & 63;     // row-group, row within group
    float s = wsum[rg * 2][local] + wsum[rg * 2 + 1][local];  // sum 2 col-halves
    atomicAdd(&out[m0 + rg * 64 + local], s);  // 8 d-tile blocks per output
  }
}

// ---- fallback (ws too small for eth_bf16): round-2 proven kernel ----
// Uses LINEAR Wb layout (written by convert_w).
#define ETH_STRIDE 40
__global__ __launch_bounds__(256, 3) void bilinear_fp32eth(const float* __restrict__ elg,
                                                           const float* __restrict__ eth,
                                                           const unsigned short* __restrict__ Wb,
                                                           float* __restrict__ out) {
  __shared__ unsigned short ethL[64 * ETH_STRIDE];
  __shared__ unsigned short Wbuf[256 * 32];
  __shared__ float wsum[4][64];
  const int tid  = threadIdx.x;
  const int lane = tid & 63;
  const int w    = tid >> 6;
  const int quad = lane >> 4;
  const int l15  = lane & 15;
  const int m0   = (blockIdx.x >> 2) * 64;
  const int d0   = (blockIdx.x & 3) * 256;
  const int erow = tid >> 2, eunit = tid & 3;
  const float* esrc = eth + (size_t)(m0 + erow) * DDIM + eunit * 8;
  const int wr = lane >> 2, wu = lane & 3;
  float4v er0 = *(const float4v*)(esrc);
  float4v er1 = *(const float4v*)(esrc + 4);
  float4v acc[4][4];
#pragma unroll
  for (int ct = 0; ct < 4; ++ct)
#pragma unroll
    for (int rt = 0; rt < 4; ++rt)
      acc[ct][rt] = (float4v){0.f, 0.f, 0.f, 0.f};
  for (int ek = 0; ek < 32; ++ek) {
    const int e0 = ek * 32;
    __syncthreads();
    {
      uint4v pk;
      pk.x = pk2(er0.x, er0.y); pk.y = pk2(er0.z, er0.w);
      pk.z = pk2(er1.x, er1.y); pk.w = pk2(er1.z, er1.w);
      *(uint4v*)&ethL[erow * ETH_STRIDE + eunit * 8] = pk;
    }
#pragma unroll
    for (int j = 0; j < 4; ++j) {
      int r  = (w * 4 + j) * 16 + wr;
      int ug = wu ^ ((r >> 1) & 3);
      const unsigned short* gp = Wb + (size_t)(d0 + r) * DDIM + e0 + ug * 8;
      unsigned short* lp = &Wbuf[(w * 4 + j) * 512 + lane * 8];
      __builtin_amdgcn_global_load_lds(
          (const __attribute__((address_space(1))) unsigned int*)gp,
          (__attribute__((address_space(3))) unsigned int*)lp, 16, 0, 0);
    }
    __syncthreads();
    short8 aF[4], bF[4];
#pragma unroll
    for (int rt = 0; rt < 4; ++rt)
      aF[rt] = *(const short8*)&ethL[(rt * 16 + l15) * ETH_STRIDE + quad * 8];
#pragma unroll
    for (int ct = 0; ct < 4; ++ct) {
      int dl = w * 64 + ct * 16 + l15;
      int pu = quad ^ ((dl >> 1) & 3);
      bF[ct] = *(const short8*)&Wbuf[dl * 32 + pu * 8];
    }
    if (ek < 31) {
      const float* s = esrc + (e0 + 32);
      er0 = *(const float4v*)(s);
      er1 = *(const float4v*)(s + 4);
    }
#pragma unroll
    for (int ct = 0; ct < 4; ++ct)
#pragma unroll
      for (int rt = 0; rt < 4; ++rt)
        acc[ct][rt] = __builtin_amdgcn_mfma_f32_16x16x32_bf16(aF[rt], bF[ct], acc[ct][rt], 0, 0, 0);
  }
  float p[16];
#pragma unroll
  for (int j = 0; j < 16; ++j) p[j] = 0.f;
#pragma unroll
  for (int ct = 0; ct < 4; ++ct) {
    int col = d0 + w * 64 + ct * 16 + l15;
#pragma unroll
    for (int rt = 0; rt < 4; ++rt) {
      const float* ep = elg + (size_t)(m0 + rt * 16 + quad * 4) * DDIM + col;
#pragma unroll
      for (int i = 0; i < 4; ++i)
        p[rt * 4 + i] += acc[ct][rt][i] * ep[(size_t)i * DDIM];
    }
  }
#pragma unroll
  for (int off = 1; off < 16; off <<= 1)
#pragma unroll
    for (int j = 0; j < 16; ++j)
      p[j] += __shfl_xor(p[j], off);
  if (l15 == 0) {
#pragma unroll
    for (int rt = 0; rt < 4; ++rt)
#pragma unroll
      for (int i = 0; i < 4; ++i)
        wsum[w][rt * 16 + quad * 4 + i] = p[rt * 4 + i];
  }
  __syncthreads();
  if (tid < 64) {
    float s = wsum[0][tid] + wsum[1][tid] + wsum[2][tid] + wsum[3][tid];
    atomicAdd(&out[m0 + tid], s);
  }
}

extern "C" void kernel_launch(void* const* d_in, const int* in_sizes, int n_in,
                              void* d_out, int out_size, void* d_ws, size_t ws_size,
                              hipStream_t stream) {
  (void)in_sizes; (void)n_in;
  const float* elg = (const float*)d_in[0];
  const float* eth = (const float*)d_in[1];
  const float* W   = (const float*)d_in[2];
  float* out = (float*)d_out;
  unsigned short* Wb   = (unsigned short*)d_ws;                      // 2 MB
  unsigned short* ethB = (unsigned short*)((char*)d_ws + (2 << 20)); // 64 MB

  const size_t need = (2ull << 20) + (64ull << 20);
  hipMemsetAsync(d_out, 0, (size_t)out_size * sizeof(float), stream);
  if (ws_size >= need) {
    convert_all<<<dim3(256 + 8192), dim3(256), 0, stream>>>(W, eth, Wb, ethB);
    bilinear_bf16<<<dim3(1024), dim3(512), 0, stream>>>(elg, ethB, Wb, out);
  } else {
    convert_w<<<dim3(512), dim3(256), 0, stream>>>(W, Wb);
    bilinear_fp32eth<<<dim3(2048), dim3(256), 0, stream>>>(elg, eth, Wb, out);
  }
}